// Round 1
// 3922.112 us; speedup vs baseline: 1.2683x; 1.2683x over previous
//
#include <hip/hip_runtime.h>
#include <math.h>

// Problem constants (fixed by the reference)
constexpr int N_ = 50000;   // nodes
constexpr int E_ = 600000;  // edges per relation
constexpr int F_ = 256;     // feature dim
constexpr int H_ = 128;     // hidden dim
constexpr int Q_ = 64;      // query dim (== one wave)
constexpr int R_ = 2;       // relations
constexpr int L_ = 2;       // conv depth

#define MODE_STORE 0
#define MODE_TANH  1
#define MODE_ACC   2

// ---------------------------------------------------------------------------
// Tiled f32 GEMM: C[M x 64*gridDim.y] = A (M x K) * B
//   BT=true : C[n,j] = sum_k A[n,k] * B[j*ldb + k]   (B^T, row-major B)
//   BT=false: C[n,j] = sum_k A[n,k] * B[k*ldb + j]
// rowscale (optional): multiply row n of the result by rowscale[n]
// Tile: 64x64, BK=16, 256 threads, 4x4 outputs/thread.
// ---------------------------------------------------------------------------
template <bool BT>
__global__ __launch_bounds__(256) void gemm_kernel(
    const float* __restrict__ A, int lda,
    const float* __restrict__ B, int ldb,
    float* __restrict__ C, int ldc,
    int M, int K,
    const float* __restrict__ rowscale, int mode)
{
    __shared__ __align__(16) float As[16][68];
    __shared__ __align__(16) float Bs[16][68];

    const int row0 = blockIdx.x * 64;
    const int col0 = blockIdx.y * 64;
    const int tid  = threadIdx.x;
    const int tm = tid >> 4;
    const int tn = tid & 15;

    float acc[4][4] = {};

    for (int kk = 0; kk < K; kk += 16) {
        {   // A tile: 64 rows x 16 k, one float4 per thread
            const int m  = tid >> 2;
            const int k4 = (tid & 3) * 4;
            const int r  = row0 + m;
            float4 v = make_float4(0.f, 0.f, 0.f, 0.f);
            if (r < M) v = *(const float4*)(A + (size_t)r * lda + kk + k4);
            As[k4 + 0][m] = v.x; As[k4 + 1][m] = v.y;
            As[k4 + 2][m] = v.z; As[k4 + 3][m] = v.w;
        }
        if (BT) {
            const int j  = tid >> 2;
            const int k4 = (tid & 3) * 4;
            float4 v = *(const float4*)(B + (size_t)(col0 + j) * ldb + kk + k4);
            Bs[k4 + 0][j] = v.x; Bs[k4 + 1][j] = v.y;
            Bs[k4 + 2][j] = v.z; Bs[k4 + 3][j] = v.w;
        } else {
            const int k  = tid >> 4;
            const int j4 = (tid & 15) * 4;
            float4 v = *(const float4*)(B + (size_t)(kk + k) * ldb + col0 + j4);
            Bs[k][j4 + 0] = v.x; Bs[k][j4 + 1] = v.y;
            Bs[k][j4 + 2] = v.z; Bs[k][j4 + 3] = v.w;
        }
        __syncthreads();

        #pragma unroll
        for (int k = 0; k < 16; k++) {
            const float4 av = *(const float4*)&As[k][tm * 4];
            const float4 bv = *(const float4*)&Bs[k][tn * 4];
            const float a[4] = {av.x, av.y, av.z, av.w};
            const float b[4] = {bv.x, bv.y, bv.z, bv.w};
            #pragma unroll
            for (int i = 0; i < 4; i++)
                #pragma unroll
                for (int j = 0; j < 4; j++)
                    acc[i][j] += a[i] * b[j];
        }
        __syncthreads();
    }

    #pragma unroll
    for (int i = 0; i < 4; i++) {
        const int r = row0 + tm * 4 + i;
        if (r >= M) continue;
        const float rs = rowscale ? rowscale[r] : 1.0f;
        #pragma unroll
        for (int j = 0; j < 4; j++) {
            const int c = col0 + tn * 4 + j;
            float v = acc[i][j] * rs;
            if (mode == MODE_TANH) v = tanhf(v);
            float* p = C + (size_t)r * ldc + c;
            if (mode == MODE_ACC) *p += v;
            else                  *p = v;
        }
    }
}

// ---------------------------------------------------------------------------
// Zero ints
// ---------------------------------------------------------------------------
__global__ __launch_bounds__(256) void zero_i(int* __restrict__ p, int n)
{
    int t = blockIdx.x * 256 + threadIdx.x;
    if (t < n) p[t] = 0;
}

// ---------------------------------------------------------------------------
// Degree counting: eb is the contiguous (R,2,E) int block for this sign.
// cnt layout: [which = r*2 + (0=src/out,1=dst/in)] x N
// ---------------------------------------------------------------------------
__global__ __launch_bounds__(256) void count_deg(const int* __restrict__ eb,
                                                 int* __restrict__ cnt, int total)
{
    int t = blockIdx.x * 256 + threadIdx.x;
    if (t >= total) return;
    int which = t / E_;
    atomicAdd(&cnt[which * N_ + eb[t]], 1);
}

// dscale[i] = rsqrt(max(cnt[i],1))
__global__ __launch_bounds__(256) void deg_finalize(const int* __restrict__ cnt,
                                                    float* __restrict__ dscale, int n)
{
    int t = blockIdx.x * 256 + threadIdx.x;
    if (t < n) {
        int v = cnt[t];
        dscale[t] = rsqrtf((float)(v < 1 ? 1 : v));
    }
}

// ---------------------------------------------------------------------------
// Exclusive scan of in-degree counts -> CSR offsets + cursor init.
// One block of 1024 threads per relation.
// ---------------------------------------------------------------------------
__global__ __launch_bounds__(1024) void scan_offs(const int* __restrict__ cnt,
                                                  int* __restrict__ offs,
                                                  int* __restrict__ cursor)
{
    __shared__ int part[1024];
    const int r = blockIdx.x;
    const int* in = cnt + (size_t)(2 * r + 1) * N_;
    int* out = offs + (size_t)r * (N_ + 1);
    int* cur = cursor + (size_t)r * N_;

    constexpr int CH = (N_ + 1023) / 1024;   // 49
    const int lo = threadIdx.x * CH;
    const int hi = (lo + CH < N_) ? lo + CH : N_;

    int s = 0;
    for (int i = lo; i < hi; i++) s += in[i];
    part[threadIdx.x] = s;
    __syncthreads();

    #pragma unroll
    for (int d = 1; d < 1024; d <<= 1) {
        int t = (threadIdx.x >= d) ? part[threadIdx.x - d] : 0;
        __syncthreads();
        part[threadIdx.x] += t;
        __syncthreads();
    }

    int run = part[threadIdx.x] - s;   // exclusive prefix at chunk start
    for (int i = lo; i < hi; i++) {
        int v = in[i];
        out[i] = run;
        cur[i] = run;
        run += v;
    }
    if (threadIdx.x == 1023) out[N_] = run;
}

// csr[r*E + pos] = src, bucketed by dst
__global__ __launch_bounds__(256) void csr_fill(const int* __restrict__ eb,
                                                int* __restrict__ cursor,
                                                int* __restrict__ csr, int total)
{
    int t = blockIdx.x * 256 + threadIdx.x;
    if (t >= total) return;
    int r = (t >= E_) ? 1 : 0;
    int e = t - r * E_;
    int s = eb[(r * 2 + 0) * E_ + e];
    int d = eb[(r * 2 + 1) * E_ + e];
    int pos = atomicAdd(&cursor[r * N_ + d], 1);
    csr[(size_t)r * E_ + pos] = s;
}

// ---------------------------------------------------------------------------
// Gather helper: sum m[csr[k]] rows over [b,e), unrolled x4 so 4 independent
// global_load_dwordx2 are in flight per wave (latency-bound random gather).
// ---------------------------------------------------------------------------
__device__ __forceinline__ void gather_rel(const float2* __restrict__ m,
                                           const int* __restrict__ csr,
                                           int b, int e, int lane, float2& acc)
{
    int k = b;
    for (; k + 4 <= e; k += 4) {
        const int s0 = csr[k + 0];
        const int s1 = csr[k + 1];
        const int s2 = csr[k + 2];
        const int s3 = csr[k + 3];
        const float2 v0 = m[(size_t)s0 * 64 + lane];
        const float2 v1 = m[(size_t)s1 * 64 + lane];
        const float2 v2 = m[(size_t)s2 * 64 + lane];
        const float2 v3 = m[(size_t)s3 * 64 + lane];
        acc.x += (v0.x + v1.x) + (v2.x + v3.x);
        acc.y += (v0.y + v1.y) + (v2.y + v3.y);
    }
    for (; k < e; k++) {
        const int s = csr[k];
        const float2 v = m[(size_t)s * 64 + lane];
        acc.x += v.x; acc.y += v.y;
    }
}

// ---------------------------------------------------------------------------
// Fused: CSR pull (both relations) + GCN finalize + relation attention.
// One wave per node; lane l holds columns {2l, 2l+1} as a float2.
//
// Occupancy fix vs previous version: 512-thread blocks so 8 waves share the
// single 32 KiB W1s copy (LDS/block ~41.5 KiB -> 3 blocks/CU = 24 waves/CU
// vs 16 before). launch_bounds(512,6) caps VGPRs at ~84 to guarantee it.
// The post-gather __syncthreads() is replaced by a wave-local
// s_waitcnt lgkmcnt(0): hsS is wave-private and lanes are lockstep, so no
// block barrier is needed -> waves are decoupled after the initial staging
// barrier (no convoy behind high-degree nodes).
// ---------------------------------------------------------------------------
__global__ __launch_bounds__(512, 6) void pull_attn(
    const float2* __restrict__ m0, const float2* __restrict__ m1,
    const int* __restrict__ offs0, const int* __restrict__ csr0,
    const int* __restrict__ offs1, const int* __restrict__ csr1,
    const float* __restrict__ si0, const float* __restrict__ si1,
    const float* __restrict__ bias0, const float* __restrict__ bias1,
    const float* __restrict__ W1, const float* __restrict__ b1,
    const float* __restrict__ w2, float2* __restrict__ outb, int n)
{
    __shared__ float W1s[H_ * Q_];          // 32 KiB, layout [i*64 + q]
    __shared__ float2 hsS[8][2][Q_];        // per-wave hs staging, 8 KiB
    __shared__ float b1s[Q_], w2s[Q_], bAs[H_], bBs[H_];

    for (int i = threadIdx.x; i < H_ * Q_; i += 512) W1s[i] = W1[i];
    if (threadIdx.x < Q_) { b1s[threadIdx.x] = b1[threadIdx.x]; w2s[threadIdx.x] = w2[threadIdx.x]; }
    {
        const int t = (int)threadIdx.x - Q_;
        if (t >= 0 && t < H_) bAs[t] = bias0[t];
        const int u = (int)threadIdx.x - Q_ - H_;
        if (u >= 0 && u < H_) bBs[u] = bias1[u];
    }
    __syncthreads();   // W1s/b1s/w2s/bAs/bBs ready; the ONLY block barrier

    const int lane = threadIdx.x & 63;
    const int wv   = threadIdx.x >> 6;
    int node = (blockIdx.x * 512 + threadIdx.x) >> 6;
    node = __builtin_amdgcn_readfirstlane(node);   // wave-uniform -> scalar loads

    float2 hs0 = make_float2(0.f, 0.f), hs1 = hs0;

    if (node < n) {
        float2 a0 = make_float2(0.f, 0.f), a1 = a0;
        const int b0  = offs0[node], e0 = offs0[node + 1];
        const int b1i = offs1[node], e1 = offs1[node + 1];
        gather_rel(m0, csr0, b0,  e0, lane, a0);
        gather_rel(m1, csr1, b1i, e1, lane, a1);

        const float sc0 = si0[node], sc1 = si1[node];
        hs0.x = a0.x * sc0 + bAs[2 * lane];
        hs0.y = a0.y * sc0 + bAs[2 * lane + 1];
        hs1.x = a1.x * sc1 + bBs[2 * lane];
        hs1.y = a1.y * sc1 + bBs[2 * lane + 1];
        hsS[wv][0][lane] = hs0;
        hsS[wv][1][lane] = hs1;
    }

    // Wave-local publish of hsS: lanes are lockstep within a wave; draining
    // lgkmcnt makes every lane's ds_write visible to every lane's ds_read.
    __asm__ volatile("s_waitcnt lgkmcnt(0)" ::: "memory");
    __builtin_amdgcn_sched_barrier(0);

    if (node < n) {
        const float* h0p = (const float*)&hsS[wv][0][0];
        const float* h1p = (const float*)&hsS[wv][1][0];
        float t0 = b1s[lane], t1 = b1s[lane];
        #pragma unroll 8
        for (int i = 0; i < H_; i++) {
            const float wval = W1s[i * Q_ + lane];
            t0 += h0p[i] * wval;
            t1 += h1p[i] * wval;
        }
        float s0 = tanhf(t0) * w2s[lane];
        float s1 = tanhf(t1) * w2s[lane];
        #pragma unroll
        for (int off = 32; off > 0; off >>= 1) {
            s0 += __shfl_xor(s0, off);
            s1 += __shfl_xor(s1, off);
        }
        const float mx = fmaxf(s0, s1);
        const float e0v = expf(s0 - mx), e1v = expf(s1 - mx);
        const float a0 = e0v / (e0v + e1v), a1 = 1.0f - a0;

        float2 o;
        o.x = a0 * hs0.x + a1 * hs1.x;
        o.y = a0 * hs0.y + a1 * hs1.y;
        outb[(size_t)node * 64 + lane] = o;
    }
}

// ---------------------------------------------------------------------------
// Orchestration
// ---------------------------------------------------------------------------
extern "C" void kernel_launch(void* const* d_in, const int* in_sizes, int n_in,
                              void* d_out, int out_size, void* d_ws, size_t ws_size,
                              hipStream_t stream)
{
    const float* x_attr = (const float*)d_in[0];
    const float* x_stru = (const float*)d_in[1];
    const int*   e_attr = (const int*)d_in[2];
    const int*   e_stru = (const int*)d_in[3];
    const float* Wf     = (const float*)d_in[4];
    const float* convW  = (const float*)d_in[5];
    const float* convB  = (const float*)d_in[6];
    const float* aW1    = (const float*)d_in[7];
    const float* aB1    = (const float*)d_in[8];
    const float* aW2    = (const float*)d_in[9];
    const float* Wc     = (const float*)d_in[10];
    float*       out    = (float*)d_out;
    float*       ws     = (float*)d_ws;

    const size_t NH = (size_t)N_ * H_;
    float* A  = ws;            // h0, later h2
    float* Bb = ws + 1 * NH;   // h1, later hA
    float* C  = ws + 2 * NH;   // m0
    float* D  = ws + 3 * NH;   // m1
    float* dscale = ws + 4 * NH;                    // 4N floats [out0,in0,out1,in1]
    int*   ibase  = (int*)(dscale + 4 * N_);
    int*   cnt    = ibase;                          // 4N ints
    int*   offs   = ibase + 4 * N_;                 // 2*(N+1)
    int*   csr    = offs + 2 * (N_ + 1);            // 2*E
    int*   cursor = csr + 2 * E_;                   // 2*N

    const int GX = (N_ + 63) / 64;
    const dim3 GGRID(GX, 2);
    const int PA_B = (N_ * 64) / 512;               // pull_attn blocks (512 thr)

    for (int run = 0; run < 4; run++) {
        const int sign = run >> 1;
        const float* x = (run & 1) ? x_stru : x_attr;
        const int* eb = ((run & 1) ? e_stru : e_attr) + (size_t)sign * (R_ * 2 * E_);
        float* y = out + (size_t)run * NH;
        const float* WcS = Wc + (size_t)sign * H_ * 3 * H_;

        // --- degrees + CSR build (once per run, reused by all 3 layers) ---
        zero_i<<<(4 * N_ + 255) / 256, 256, 0, stream>>>(cnt, 4 * N_);
        count_deg<<<(4 * E_ + 255) / 256, 256, 0, stream>>>(eb, cnt, 4 * E_);
        deg_finalize<<<(4 * N_ + 255) / 256, 256, 0, stream>>>(cnt, dscale, 4 * N_);
        scan_offs<<<2, 1024, 0, stream>>>(cnt, offs, cursor);
        csr_fill<<<(2 * E_ + 255) / 256, 256, 0, stream>>>(eb, cursor, csr, 2 * E_);

        // --- h0 = tanh(x @ Wf^T) ---
        gemm_kernel<true><<<GGRID, 256, 0, stream>>>(
            x, F_, Wf + (size_t)sign * H_ * F_, F_, A, H_, N_, F_, nullptr, MODE_TANH);

        // --- y = h0 @ Wc[:, 0:H]^T ---
        gemm_kernel<true><<<GGRID, 256, 0, stream>>>(
            A, H_, WcS, 3 * H_, y, H_, N_, H_, nullptr, MODE_STORE);

        // --- heterogeneous layer: m GEMMs + fused pull/attention ---
        auto het = [&](const float* h_in, int l, float* outb) {
            const size_t lo = (size_t)(sign * L_ + l);
            for (int r = 0; r < R_; r++) {
                const float* W = convW + (lo * R_ + r) * H_ * H_;
                gemm_kernel<false><<<GGRID, 256, 0, stream>>>(
                    h_in, H_, W, H_, r ? D : C, H_, N_, H_,
                    dscale + (size_t)(2 * r) * N_, MODE_STORE);
            }
            pull_attn<<<PA_B, 512, 0, stream>>>(
                (const float2*)C, (const float2*)D,
                offs, csr, offs + (N_ + 1), csr + E_,
                dscale + N_, dscale + 3 * N_,
                convB + (lo * R_ + 0) * H_, convB + (lo * R_ + 1) * H_,
                aW1 + lo * H_ * Q_, aB1 + lo * Q_, aW2 + lo * Q_,
                (float2*)outb, N_);
        };

        // --- h1 = het(h0, layer 1); y += h1 @ Wc[:, H:2H]^T ---
        het(A, 1, Bb);
        gemm_kernel<true><<<GGRID, 256, 0, stream>>>(
            Bb, H_, WcS + H_, 3 * H_, y, H_, N_, H_, nullptr, MODE_ACC);

        // --- hA = het(h0, layer 0) (h1 consumed, reuse Bb) ---
        het(A, 0, Bb);

        // --- h2 = het(hA, layer 1) -> A (h0 dead); y += h2 @ Wc[:, 2H:3H]^T ---
        het(Bb, 1, A);
        gemm_kernel<true><<<GGRID, 256, 0, stream>>>(
            A, H_, WcS + 2 * H_, 3 * H_, y, H_, N_, H_, nullptr, MODE_ACC);
    }
}